// Round 7
// baseline (221.799 us; speedup 1.0000x reference)
//
#include <hip/hip_runtime.h>
#include <math.h>

typedef unsigned short u16;
typedef unsigned int u32;
typedef __attribute__((ext_vector_type(8))) short bf16x8;
typedef __attribute__((ext_vector_type(4))) float f32x4;

#define TT   4096   // tokens
#define DM   512    // model dim
#define NE   64     // routed experts
#define HE   256    // expert hidden (also pseudo-expert slice of shared)
#define HSH  2048   // shared expert hidden = 8 * 256
#define NSH  8      // shared pseudo-experts
#define PADBASE 16384          // shared tile b0 encoding base
#define MAXTILES 384           // <=128 routed (M=128) + 256 shared
#define MAXRT    128           // max routed tiles

#define WAITV(N) asm volatile("s_waitcnt vmcnt(" #N ")" ::: "memory")
#define SBAR()   __builtin_amdgcn_s_barrier()
#define SCHEDB() __builtin_amdgcn_sched_barrier(0)

__device__ __forceinline__ float sig_(float z){ return 1.f/(1.f+__expf(-z)); }

__device__ __forceinline__ u16 f2bf(float x){
  u32 u = __builtin_bit_cast(u32, x);
  u = (u + 0x7FFFu + ((u >> 16) & 1u)) >> 16;
  return (u16)u;
}

__device__ __forceinline__ f32x4 mfma16(bf16x8 a, bf16x8 b, f32x4 c){
  return __builtin_amdgcn_mfma_f32_16x16x32_bf16(a, b, c, 0, 0, 0);
}

// swizzled fragment read: tile row-major [rows][64B]; csw = pre-swizzled chunk byte off
__device__ __forceinline__ bf16x8 frd(const char* tile, int row, int csw){
  return *(const bf16x8*)(tile + row*64 + csw);
}

// async global->LDS, 16B per lane; lds dest = wave-uniform base + lane*16
__device__ __forceinline__ void gl16(const void* g, void* l){
  __builtin_amdgcn_global_load_lds(
      (const __attribute__((address_space(1))) unsigned int*)g,
      (__attribute__((address_space(3))) unsigned int*)l, 16, 0, 0);
}

// ---------------------------------------------------------------------------
// Fused pre-pass: 6 transpose-convert jobs + ln_gate, one launch.
// cvt: fp32 [K][N] -> bf16 [N][K]; NO LDS: thread owns (n, k0..k0+63).
// Wave reads 64 consecutive n per k (coalesced); writes 16B chunks that tile
// two full 64B lines per thread. Fold: fout[n] += sum_k fvec[k]*W[k][n].
// ---------------------------------------------------------------------------
struct CvtJob {
  const float* in; const float* scale; const float* fvec;
  u16* out; float* fout; int K; int N; int base;
};
struct CvtJobs { CvtJob j[6]; };

__global__ __launch_bounds__(256) void k_pre(
    CvtJobs jobs, int ln_base,
    const float* __restrict__ x, const float* __restrict__ Wg,
    const float* __restrict__ bg,
    u16* __restrict__ nxb, int* __restrict__ top_idx, float* __restrict__ top_w)
{
  const int bid = blockIdx.x;
  const int tid = threadIdx.x;

  if (bid < ln_base){
    // ---------------- convert/transpose path (no LDS) ----------------
    int ji = 0;
    #pragma unroll
    for (int i = 1; i < 6; i++) ji = (bid >= jobs.j[i].base) ? i : ji;
    const CvtJob J = jobs.j[ji];
    const int local = bid - J.base;
    const int nbk = J.K >> 6;         // 64-k tiles
    const int nbn = J.N >> 8;         // 256-n tiles
    const int pm = nbk * nbn;
    const int z = local / pm, rem = local - z*pm;
    const int kt = rem % nbk, ntile = rem / nbk;
    const int k0 = kt*64;
    const int n  = ntile*256 + tid;

    const float* src = J.in + (size_t)z*J.K*J.N + (size_t)k0*J.N + n;
    const float* scp = J.scale ? (J.scale + (size_t)z*J.K + k0) : nullptr;
    const float* fvp = J.fvec  ? (J.fvec  + (size_t)z*J.K + k0) : nullptr;
    u16* dst = J.out + (size_t)z*J.K*J.N + (size_t)n*J.K + k0;

    float fsum = 0.f;
    for (int kk = 0; kk < 8; kk++){
      float v[8];
      #pragma unroll
      for (int j = 0; j < 8; j++) v[j] = src[(size_t)(kk*8 + j)*J.N];
      u16 b[8];
      if (scp){
        #pragma unroll
        for (int j = 0; j < 8; j++) b[j] = f2bf(v[j]*scp[kk*8 + j]);
      } else {
        #pragma unroll
        for (int j = 0; j < 8; j++) b[j] = f2bf(v[j]);
      }
      if (fvp){
        #pragma unroll
        for (int j = 0; j < 8; j++) fsum += v[j]*fvp[kk*8 + j];
      }
      uint4 pk;
      pk.x = (u32)b[0] | ((u32)b[1] << 16);
      pk.y = (u32)b[2] | ((u32)b[3] << 16);
      pk.z = (u32)b[4] | ((u32)b[5] << 16);
      pk.w = (u32)b[6] | ((u32)b[7] << 16);
      *(uint4*)(dst + kk*8) = pk;
    }
    if (J.fout) atomicAdd(J.fout + (size_t)z*J.N + n, fsum);
    return;
  }

  // ---------------- LN + gate + top-2 path ----------------
  __shared__ float xs[DM];
  __shared__ float sred[4], ssred[4];
  __shared__ float sc[NE];
  const int t = bid - ln_base;

  float2 v = reinterpret_cast<const float2*>(x + (size_t)t*DM)[tid];
  xs[2*tid]   = v.x;
  xs[2*tid+1] = v.y;
  float s  = v.x + v.y;
  float ss = v.x*v.x + v.y*v.y;
  #pragma unroll
  for (int o = 32; o > 0; o >>= 1){ s += __shfl_xor(s, o); ss += __shfl_xor(ss, o); }
  const int wid = tid >> 6, lane = tid & 63;
  if (lane == 0){ sred[wid] = s; ssred[wid] = ss; }
  __syncthreads();
  const float tot = sred[0]+sred[1]+sred[2]+sred[3];
  const float tss = ssred[0]+ssred[1]+ssred[2]+ssred[3];
  const float mu  = tot * (1.f/DM);
  const float var = tss * (1.f/DM) - mu*mu;
  const float rstd = rsqrtf(var + 1e-5f);
  u32 pk = (u32)f2bf((v.x-mu)*rstd) | ((u32)f2bf((v.y-mu)*rstd) << 16);
  *(u32*)(nxb + (size_t)t*DM + 2*tid) = pk;

  const int e = tid >> 2, sub = tid & 3;
  const float4* wrow4 = reinterpret_cast<const float4*>(Wg + (size_t)e*DM);
  const float4* xs4   = reinterpret_cast<const float4*>(xs);
  float acc = 0.f;
  #pragma unroll 4
  for (int i = sub; i < DM/4; i += 4){
    const float4 w = wrow4[i]; const float4 xv = xs4[i];
    acc += xv.x*w.x + xv.y*w.y + xv.z*w.z + xv.w*w.w;
  }
  acc += __shfl_xor(acc, 1);
  acc += __shfl_xor(acc, 2);
  if (sub == 0) sc[e] = acc + bg[e];
  __syncthreads();

  if (tid < 64) {
    const float s0 = sc[tid];
    float m = s0; int mi = tid;
    #pragma unroll
    for (int o = 1; o < 64; o <<= 1){
      float om = __shfl_xor(m, o); int oi = __shfl_xor(mi, o);
      if (om > m || (om == m && oi < mi)) { m = om; mi = oi; }
    }
    float s1 = (tid == mi) ? -INFINITY : s0;
    float m2 = s1; int mi2 = tid;
    #pragma unroll
    for (int o = 1; o < 64; o <<= 1){
      float om = __shfl_xor(m2, o); int oi = __shfl_xor(mi2, o);
      if (om > m2 || (om == m2 && oi < mi2)) { m2 = om; mi2 = oi; }
    }
    if (tid == 0){
      const float w0 = sig_(m), w1 = sig_(m2);
      const float inv = 1.f/(w0+w1);
      top_idx[2*t]   = mi;
      top_idx[2*t+1] = mi2;
      top_w[2*t]     = w0*inv;
      top_w[2*t+1]   = w1*inv;
    }
  }
}

// ---------------------------------------------------------------------------
// Kernel 2: routing. Padded (M=128) per-expert bases, scatter, tile list.
// ---------------------------------------------------------------------------
__global__ __launch_bounds__(256) void k_route(
    const int* __restrict__ top_idx, const float* __restrict__ top_w,
    int* __restrict__ bucket_tok, float* __restrict__ bucket_w,
    int* __restrict__ tiles, int* __restrict__ n_tiles)
{
  __shared__ int cnt[NE], base_[NE];
  __shared__ int nroute;
  const int tid = threadIdx.x;
  if (tid < NE) cnt[tid] = 0;
  __syncthreads();
  for (int p = tid; p < TT*2; p += 256) atomicAdd(&cnt[top_idx[p]], 1);
  __syncthreads();
  if (tid == 0){
    int run = 0, ntl = 0;
    for (int e = 0; e < NE; e++){
      base_[e] = run;
      const int c = cnt[e];
      for (int b = 0; b < c; b += 128){
        const int n = (c - b < 128) ? (c - b) : 128;
        tiles[ntl++] = (e << 17) | (((run + b) >> 7) << 8) | n;
      }
      run += ((c + 127) >> 7) << 7;   // padded advance
    }
    nroute = ntl;
    n_tiles[0] = ntl + NSH*(TT/128);
    n_tiles[1] = ntl;
  }
  __syncthreads();
  if (tid < NSH*(TT/128)){
    const int s = tid >> 5, t = tid & 31;     // TT/128 = 32
    const int b0 = PADBASE + s*TT + t*128;
    tiles[nroute + tid] = ((NE + s) << 17) | ((b0 >> 7) << 8) | 128;
  }
  if (tid < NE) cnt[tid] = 0;
  __syncthreads();
  for (int p = tid; p < TT*2; p += 256){
    const int e = top_idx[p];
    const int pos = base_[e] + atomicAdd(&cnt[e], 1);
    bucket_tok[pos] = p >> 1;
    bucket_w[pos]   = top_w[p];
  }
}

// ---------------------------------------------------------------------------
// Kernel 3: unified up-proj. M=128, N=128 (HE half via blockIdx.y), K=512,
// BK=32. 3-buffer counted-vmcnt pipeline + LDS XOR swizzle. 512 thr, 8 waves.
// ---------------------------------------------------------------------------
__global__ __launch_bounds__(512) void k_up(
    const u16* __restrict__ nxb,
    const u16* __restrict__ W1bT, const u16* __restrict__ W3bT,
    const u16* __restrict__ Ws1bT, const u16* __restrict__ Ws3bT,
    const float* __restrict__ b1, const float* __restrict__ b3,
    const float* __restrict__ bs1, const float* __restrict__ bs3,
    const float* __restrict__ b1f, const float* __restrict__ b3f,
    const int* __restrict__ bucket_tok, const float* __restrict__ bucket_w,
    const int* __restrict__ tiles, const int* __restrict__ n_tiles,
    u16* __restrict__ hrout, u16* __restrict__ hs)
{
  if ((int)blockIdx.x >= n_tiles[0]) return;
  const int info = tiles[blockIdx.x];
  const int e  = info >> 17;
  const int b0 = ((info >> 8) & 0x1FF) << 7;
  const int nt = info & 255;
  const bool sh = (e >= NE);
  const int y  = blockIdx.y;            // HE half

  __shared__ __align__(16) char Ab[3][8192];
  __shared__ __align__(16) char B1b[3][8192];
  __shared__ __align__(16) char B3b[3][8192];
  __shared__ int   toks[128];
  __shared__ float tw[128];

  const int tid = threadIdx.x, wid = tid >> 6, lane = tid & 63;
  const int l15 = lane & 15, q = lane >> 4;

  if (tid < 128){
    int tk; float w;
    if (!sh){
      if (tid < nt){ tk = bucket_tok[b0+tid]; w = bucket_w[b0+tid]; }
      else         { tk = 0; w = 0.f; }
    } else {
      tk = ((b0 - PADBASE) & (TT-1)) + tid; w = 1.f;
    }
    toks[tid] = tk; tw[tid] = w;
  }
  __syncthreads();

  const u16* w1e = sh ? (Ws1bT + (size_t)(e-NE)*HE*DM) : (W1bT + (size_t)e*HE*DM);
  const u16* w3e = sh ? (Ws3bT + (size_t)(e-NE)*HE*DM) : (W3bT + (size_t)e*HE*DM);

  const int srow = lane >> 2;
  const int csrc = (((lane & 3) ^ ((lane >> 3) & 3))) * 8;
  const u16* asrc = nxb + (size_t)toks[wid*16 + srow]*DM + csrc;
  const u16* b1s  = w1e + (size_t)(y*128 + wid*16 + srow)*DM + csrc;
  const u16* b3s  = w3e + (size_t)(y*128 + wid*16 + srow)*DM + csrc;
  const int loff = wid*1024;

#define UP_STAGE(ph, k0) do{ \
    gl16(asrc + (k0), Ab[ph] + loff); \
    gl16(b1s  + (k0), B1b[ph] + loff); \
    gl16(b3s  + (k0), B3b[ph] + loff); \
  } while(0)

  const int wm = (wid & 1)*64, wn = (wid >> 1)*32;

  const float* ob1 = sh ? (bs1 + (size_t)(e-NE)*HE) : (b1 + (size_t)e*HE);
  const float* ob3 = sh ? (bs3 + (size_t)(e-NE)*HE) : (b3 + (size_t)e*HE);
  f32x4 acc1[4][2], acc3[4][2];
  #pragma unroll
  for (int fn = 0; fn < 2; fn++){
    const int h = y*128 + wn + fn*16 + l15;
    const float v1 = ob1[h] + b1f[(size_t)e*HE + h];
    const float v3 = ob3[h] + b3f[(size_t)e*HE + h];
    #pragma unroll
    for (int fm = 0; fm < 4; fm++){
      acc1[fm][fn] = (f32x4){v1,v1,v1,v1};
      acc3[fm][fn] = (f32x4){v3,v3,v3,v3};
    }
  }

  UP_STAGE(0, 0);
  UP_STAGE(1, 32);
  const int csw = (q ^ ((l15 >> 1) & 3)) * 16;

  for (int ks = 0; ks < DM/32; ks++){
    const int cur = ks % 3;
    if (ks + 2 < DM/32) UP_STAGE((ks+2)%3, (ks+2)*32);
    if (ks < DM/32 - 2)       WAITV(6);
    else if (ks == DM/32 - 2) WAITV(3);
    else                      WAITV(0);
    SBAR();
    __builtin_amdgcn_s_setprio(1);
    const char* A  = Ab[cur];
    const char* B1 = B1b[cur];
    const char* B3 = B3b[cur];
    bf16x8 fa[4];
    #pragma unroll
    for (int fm = 0; fm < 4; fm++) fa[fm] = frd(A, wm + fm*16 + l15, csw);
    #pragma unroll
    for (int fn = 0; fn < 2; fn++){
      bf16x8 fb1 = frd(B1, wn + fn*16 + l15, csw);
      bf16x8 fb3 = frd(B3, wn + fn*16 + l15, csw);
      #pragma unroll
      for (int fm = 0; fm < 4; fm++){
        acc1[fm][fn] = mfma16(fa[fm], fb1, acc1[fm][fn]);
        acc3[fm][fn] = mfma16(fa[fm], fb3, acc3[fm][fn]);
      }
    }
    __builtin_amdgcn_s_setprio(0);
    SCHEDB();
    SBAR();
  }
#undef UP_STAGE

  const int tbase = sh ? ((b0 - PADBASE) & (TT-1)) : 0;
  const int scol  = sh ? (e - NE)*HE : 0;
  #pragma unroll
  for (int fm = 0; fm < 4; fm++){
    #pragma unroll
    for (int fn = 0; fn < 2; fn++){
      const int hl = y*128 + wn + fn*16 + l15;
      #pragma unroll
      for (int r = 0; r < 4; r++){
        const int m = wm + fm*16 + 4*q + r;
        float v = 0.f;
        if (m < nt){
          const float a1 = acc1[fm][fn][r];
          const float a3 = acc3[fm][fn][r];
          v = a1 * sig_(a1) * a3 * tw[m];
        }
        if (sh) hs[(size_t)(tbase+m)*HSH + scol + hl] = f2bf(v);
        else    hrout[(size_t)(b0+m)*HE + hl] = f2bf(v);
      }
    }
  }
}

// ---------------------------------------------------------------------------
// Kernel 4 (merged down): out was memset to 0; both paths atomicAdd.
//  blocks [0,128):   shared down. M=128 (t), N=128 (d), K=2048. G=2.
//  blocks [128,384): routed down. M=128 slots, N=256 (DM half), K=256. G=3.
// 512 threads, 8 waves (2M x 4N).
// ---------------------------------------------------------------------------
__global__ __launch_bounds__(512) void k_down(
    const u16* __restrict__ hs, const u16* __restrict__ Ws2bT,
    const float* __restrict__ bs2,
    const u16* __restrict__ hrout, const u16* __restrict__ W2bT,
    const float* __restrict__ b2,
    const int* __restrict__ bucket_tok, const float* __restrict__ bucket_w,
    const int* __restrict__ tiles, const int* __restrict__ n_tiles,
    float* __restrict__ out)
{
  __shared__ __align__(16) char LDS[73728];   // max(3*8K+3*8K, 3*8K+3*16K)
  __shared__ int   toks[128];
  __shared__ float tw[128];

  const int tid = threadIdx.x, wid = tid >> 6, lane = tid & 63;
  const int l15 = lane & 15, q = lane >> 4;
  const int csw  = (q ^ ((l15 >> 1) & 3)) * 16;
  const int srow = tid >> 2;
  const int csrc = ((tid & 3) ^ ((tid >> 3) & 3)) * 8;
  const int loff = wid*1024;

  if ((int)blockIdx.x < 128){
    // ---------------- shared expert down ----------------
    const int t0 = (blockIdx.x >> 2) * 128;
    const int d0 = (blockIdx.x & 3) * 128;
    char* Ab = LDS;            // 3 x 8192
    char* Bb = LDS + 24576;    // 3 x 8192

    const u16* asrc = hs    + (size_t)(t0 + srow)*HSH + csrc;
    const u16* bsrc = Ws2bT + (size_t)(d0 + srow)*HSH + csrc;

#define DS_STAGE(ph, k0) do{ \
    gl16(asrc + (k0), Ab + (ph)*8192 + loff); \
    gl16(bsrc + (k0), Bb + (ph)*8192 + loff); \
  } while(0)

    const int wm = (wid & 1)*64, wn = (wid >> 1)*32;

    f32x4 acc[4][2];
    #pragma unroll
    for (int fm = 0; fm < 4; fm++)
      #pragma unroll
      for (int fn = 0; fn < 2; fn++) acc[fm][fn] = (f32x4){0.f,0.f,0.f,0.f};

    DS_STAGE(0, 0);
    DS_STAGE(1, 32);

    for (int ks = 0; ks < HSH/32; ks++){
      const int cur = ks % 3;
      if (ks + 2 < HSH/32) DS_STAGE((ks+2)%3, (ks+2)*32);
      if (ks < HSH/32 - 2)       WAITV(4);
      else if (ks == HSH/32 - 2) WAITV(2);
      else                       WAITV(0);
      SBAR();
      __builtin_amdgcn_s_setprio(1);
      const char* A = Ab + cur*8192;
      const char* B = Bb + cur*8192;
      bf16x8 fa[4];
      #pragma unroll
      for (int fm = 0; fm < 4; fm++) fa[fm] = frd(A, wm + fm*16 + l15, csw);
      #pragma unroll
      for (int fn = 0; fn < 2; fn++){
        bf16x8 fb = frd(B, wn + fn*16 + l15, csw);
        #pragma unroll
        for (int fm = 0; fm < 4; fm++)
          acc[fm][fn] = mfma16(fa[fm], fb, acc[fm][fn]);
      }
      __builtin_amdgcn_s_setprio(0);
      SCHEDB();
      SBAR();
    }
#undef DS_STAGE

    #pragma unroll
    for (int fm = 0; fm < 4; fm++){
      #pragma unroll
      for (int fn = 0; fn < 2; fn++){
        const int d = d0 + wn + fn*16 + l15;
        const float bv = bs2[d];
        #pragma unroll
        for (int r = 0; r < 4; r++){
          const int t = t0 + wm + fm*16 + 4*q + r;
          atomicAdd(out + (size_t)t*DM + d, acc[fm][fn][r] + bv);
        }
      }
    }
    return;
  }

  // ---------------- routed down ----------------
  const int rb = (int)blockIdx.x - 128;
  const int ti = rb >> 1;
  if (ti >= n_tiles[1]) return;
  const int info = tiles[ti];
  const int e  = info >> 17;
  const int b0 = ((info >> 8) & 0x1FF) << 7;
  const int nt = info & 255;
  const int d0 = (rb & 1) * 256;

  char* Ab = LDS;            // 3 x 8192
  char* Bb = LDS + 24576;    // 3 x 16384

  if (tid < 128){
    if (tid < nt){ toks[tid] = bucket_tok[b0+tid]; tw[tid] = bucket_w[b0+tid]; }
    else         { toks[tid] = 0; tw[tid] = 0.f; }
  }
  __syncthreads();

  const u16* w2e = W2bT + (size_t)e*DM*HE;
  const u16* asrc  = hrout + (size_t)(b0 + srow)*HE + csrc;
  const u16* bsrc0 = w2e + (size_t)(d0 + srow)*HE + csrc;
  const u16* bsrc1 = w2e + (size_t)(d0 + 128 + srow)*HE + csrc;

#define DR_STAGE(ph, k0) do{ \
    gl16(asrc  + (k0), Ab + (ph)*8192  + loff); \
    gl16(bsrc0 + (k0), Bb + (ph)*16384 + loff); \
    gl16(bsrc1 + (k0), Bb + (ph)*16384 + 8192 + loff); \
  } while(0)

  const int wm = (wid & 1)*64, wn = (wid >> 1)*64;

  f32x4 acc[4][4];
  #pragma unroll
  for (int fm = 0; fm < 4; fm++)
    #pragma unroll
    for (int fn = 0; fn < 4; fn++) acc[fm][fn] = (f32x4){0.f,0.f,0.f,0.f};

  DR_STAGE(0, 0);
  DR_STAGE(1, 32);

  for (int ks = 0; ks < HE/32; ks++){
    const int cur = ks % 3;
    if (ks + 2 < HE/32) DR_STAGE((ks+2)%3, (ks+2)*32);
    if (ks < HE/32 - 2)       WAITV(6);
    else if (ks == HE/32 - 2) WAITV(3);
    else                      WAITV(0);
    SBAR();
    __builtin_amdgcn_s_setprio(1);
    const char* A = Ab + cur*8192;
    const char* B = Bb + cur*16384;
    bf16x8 fa[4];
    #pragma unroll
    for (int fm = 0; fm < 4; fm++) fa[fm] = frd(A, wm + fm*16 + l15, csw);
    #pragma unroll
    for (int fn = 0; fn < 4; fn++){
      bf16x8 fb = frd(B, wn + fn*16 + l15, csw);
      #pragma unroll
      for (int fm = 0; fm < 4; fm++)
        acc[fm][fn] = mfma16(fa[fm], fb, acc[fm][fn]);
    }
    __builtin_amdgcn_s_setprio(0);
    SCHEDB();
    SBAR();
  }
#undef DR_STAGE

  #pragma unroll
  for (int fm = 0; fm < 4; fm++){
    #pragma unroll
    for (int fn = 0; fn < 4; fn++){
      const int d = d0 + wn + fn*16 + l15;
      #pragma unroll
      for (int r = 0; r < 4; r++){
        const int m = wm + fm*16 + 4*q + r;
        if (m < nt)
          atomicAdd(out + (size_t)toks[m]*DM + d, acc[fm][fn][r] + tw[m]*b2[(size_t)e*DM + d]);
      }
    }
  }
}

// ---------------------------------------------------------------------------
extern "C" void kernel_launch(void* const* d_in, const int* in_sizes, int n_in,
                              void* d_out, int out_size, void* d_ws, size_t ws_size,
                              hipStream_t stream)
{
  (void)in_sizes; (void)n_in; (void)ws_size;
  const float* x     = (const float*)d_in[0];
  const float* Wg    = (const float*)d_in[1];
  const float* bg    = (const float*)d_in[2];
  const float* gamma = (const float*)d_in[3];
  const float* beta  = (const float*)d_in[4];
  const float* W1    = (const float*)d_in[5];
  const float* b1    = (const float*)d_in[6];
  const float* W3    = (const float*)d_in[7];
  const float* b3    = (const float*)d_in[8];
  const float* W2    = (const float*)d_in[9];
  const float* b2    = (const float*)d_in[10];
  const float* gs    = (const float*)d_in[11];
  const float* bs    = (const float*)d_in[12];
  const float* Ws1   = (const float*)d_in[13];
  const float* bs1   = (const float*)d_in[14];
  const float* Ws3   = (const float*)d_in[15];
  const float* bs3   = (const float*)d_in[16];
  const float* Ws2   = (const float*)d_in[17];
  const float* bs2   = (const float*)d_in[18];
  float* out = (float*)d_out;

  char* ws = (char*)d_ws;
  size_t off = 0;
  auto alloc = [&](size_t bytes) -> char* {
    char* p = ws + off;
    off += (bytes + 255) & ~(size_t)255;
    return p;
  };
  u16*   nxb        = (u16*)  alloc((size_t)TT*DM*2);
  int*   top_idx    = (int*)  alloc((size_t)TT*2*4);
  float* top_w      = (float*)alloc((size_t)TT*2*4);
  int*   bucket_tok = (int*)  alloc((size_t)PADBASE*4);
  float* bucket_w   = (float*)alloc((size_t)PADBASE*4);
  int*   tiles      = (int*)  alloc(MAXTILES*4);
  int*   n_tiles    = (int*)  alloc(64);
  u16*   hrout      = (u16*)  alloc((size_t)PADBASE*HE*2);
  u16*   hs         = (u16*)  alloc((size_t)TT*HSH*2);
  u16*   W1bT       = (u16*)  alloc((size_t)NE*HE*DM*2);
  u16*   W3bT       = (u16*)  alloc((size_t)NE*HE*DM*2);
  u16*   W2bT       = (u16*)  alloc((size_t)NE*DM*HE*2);
  u16*   Ws1bT      = (u16*)  alloc((size_t)HSH*DM*2);
  u16*   Ws3bT      = (u16*)  alloc((size_t)HSH*DM*2);
  u16*   Ws2bT      = (u16*)  alloc((size_t)DM*HSH*2);
  float* b1f        = (float*)alloc((size_t)(NE*HE + HSH)*4);
  float* b3f        = (float*)alloc((size_t)(NE*HE + HSH)*4);

  // --- memsets ---
  hipMemsetAsync(b1f, 0, (size_t)(NE*HE + HSH)*4, stream);
  hipMemsetAsync(b3f, 0, (size_t)(NE*HE + HSH)*4, stream);
  hipMemsetAsync(out, 0, (size_t)out_size*sizeof(float), stream);

  // --- fused pre-pass: convert/transpose + folds + LN/gate (one launch) ---
  CvtJobs jobs;
  // bases: blocks per job = Z * (K/64) * (N/256)
  jobs.j[0] = { W1,  gamma,   beta,    W1bT,  b1f,          DM,  HE,  0    }; // 512
  jobs.j[1] = { W3,  gamma,   beta,    W3bT,  b3f,          DM,  HE,  512  }; // 512
  jobs.j[2] = { W2,  nullptr, nullptr, W2bT,  nullptr,      HE,  DM,  1024 }; // 512
  jobs.j[3] = { Ws1, gs,      bs,      Ws1bT, b1f + NE*HE,  DM,  HSH, 1536 }; // 64
  jobs.j[4] = { Ws3, gs,      bs,      Ws3bT, b3f + NE*HE,  DM,  HSH, 1600 }; // 64
  jobs.j[5] = { Ws2, nullptr, nullptr, Ws2bT, nullptr,      HSH, DM,  1664 }; // 64
  const int ln_base = 1728;
  k_pre<<<dim3(ln_base + TT), 256, 0, stream>>>(jobs, ln_base,
                                                x, Wg, bg, nxb, top_idx, top_w);

  // --- routing ---
  k_route<<<dim3(1), 256, 0, stream>>>(top_idx, top_w, bucket_tok, bucket_w, tiles, n_tiles);

  // --- expert GEMMs ---
  k_up<<<dim3(MAXTILES, 2), 512, 0, stream>>>(nxb, W1bT, W3bT, Ws1bT, Ws3bT,
                                              b1, b3, bs1, bs3, b1f, b3f,
                                              bucket_tok, bucket_w, tiles, n_tiles, hrout, hs);
  k_down<<<dim3(384), 512, 0, stream>>>(hs, Ws2bT, bs2, hrout, W2bT, b2,
                                        bucket_tok, bucket_w, tiles, n_tiles, out);
}

// Round 8
// 198.079 us; speedup vs baseline: 1.1198x; 1.1198x over previous
//
#include <hip/hip_runtime.h>
#include <math.h>

typedef unsigned short u16;
typedef unsigned int u32;
typedef __attribute__((ext_vector_type(8))) short bf16x8;
typedef __attribute__((ext_vector_type(4))) float f32x4;

#define TT   4096   // tokens
#define DM   512    // model dim
#define NE   64     // routed experts
#define HE   256    // expert hidden (also pseudo-expert slice of shared)
#define HSH  2048   // shared expert hidden = 8 * 256
#define NSH  8      // shared pseudo-experts
#define PADBASE 16384          // shared tile b0 encoding base
#define MAXTILES 384           // <=128 routed (M=128) + 256 shared
#define MAXRT    128           // max routed tiles

#define WAITV(N) asm volatile("s_waitcnt vmcnt(" #N ")" ::: "memory")
#define SBAR()   __builtin_amdgcn_s_barrier()
#define SCHEDB() __builtin_amdgcn_sched_barrier(0)

__device__ __forceinline__ float sig_(float z){ return 1.f/(1.f+__expf(-z)); }

__device__ __forceinline__ u16 f2bf(float x){
  u32 u = __builtin_bit_cast(u32, x);
  u = (u + 0x7FFFu + ((u >> 16) & 1u)) >> 16;
  return (u16)u;
}

__device__ __forceinline__ f32x4 mfma16(bf16x8 a, bf16x8 b, f32x4 c){
  return __builtin_amdgcn_mfma_f32_16x16x32_bf16(a, b, c, 0, 0, 0);
}

// swizzled fragment read: tile row-major [rows][64B]; csw = pre-swizzled chunk byte off
__device__ __forceinline__ bf16x8 frd(const char* tile, int row, int csw){
  return *(const bf16x8*)(tile + row*64 + csw);
}

// async global->LDS, 16B per lane; lds dest = wave-uniform base + lane*16
__device__ __forceinline__ void gl16(const void* g, void* l){
  __builtin_amdgcn_global_load_lds(
      (const __attribute__((address_space(1))) unsigned int*)g,
      (__attribute__((address_space(3))) unsigned int*)l, 16, 0, 0);
}

// ---------------------------------------------------------------------------
// Fused pre-pass: 6 transpose-convert jobs + ln_gate, one launch.
// cvt: fp32 [K][N] -> bf16 [N][K]. Thread owns (n, k0..k0+63): coalesced fp32
// column reads, register convert/pack, LDS redistribution (144B row stride,
// 2-way max = free), then 128B-contiguous-per-8-lanes stores (no partial
// sectors). Fold: fout[n] += sum_k fvec[k]*W[k][n].
// ---------------------------------------------------------------------------
struct CvtJob {
  const float* in; const float* scale; const float* fvec;
  u16* out; float* fout; int K; int N; int base;
};
struct CvtJobs { CvtJob j[6]; };

__global__ __launch_bounds__(256) void k_pre(
    CvtJobs jobs, int ln_base,
    const float* __restrict__ x, const float* __restrict__ Wg,
    const float* __restrict__ bg,
    u16* __restrict__ nxb, int* __restrict__ top_idx, float* __restrict__ top_w)
{
  __shared__ __align__(16) char LT[256*144];   // 36 KB transpose staging
  const int bid = blockIdx.x;
  const int tid = threadIdx.x;

  if (bid < ln_base){
    // ---------------- convert/transpose path ----------------
    int ji = 0;
    #pragma unroll
    for (int i = 1; i < 6; i++) ji = (bid >= jobs.j[i].base) ? i : ji;
    const CvtJob J = jobs.j[ji];
    const int local = bid - J.base;
    const int nbk = J.K >> 6;         // 64-k tiles
    const int nbn = J.N >> 8;         // 256-n tiles
    const int pm = nbk * nbn;
    const int z = local / pm, rem = local - z*pm;
    const int kt = rem % nbk, ntile = rem / nbk;
    const int k0 = kt*64;
    const int n  = ntile*256 + tid;

    const float* src = J.in + (size_t)z*J.K*J.N + (size_t)k0*J.N + n;
    const float* scp = J.scale ? (J.scale + (size_t)z*J.K + k0) : nullptr;
    const float* fvp = J.fvec  ? (J.fvec  + (size_t)z*J.K + k0) : nullptr;

    // phase 1: read coalesced, convert in regs, stage to LDS (2-way free)
    float fsum = 0.f;
    #pragma unroll 2
    for (int kk = 0; kk < 8; kk++){
      float v[8];
      #pragma unroll
      for (int j = 0; j < 8; j++) v[j] = src[(size_t)(kk*8 + j)*J.N];
      u16 b[8];
      if (scp){
        #pragma unroll
        for (int j = 0; j < 8; j++) b[j] = f2bf(v[j]*scp[kk*8 + j]);
      } else {
        #pragma unroll
        for (int j = 0; j < 8; j++) b[j] = f2bf(v[j]);
      }
      if (fvp){
        #pragma unroll
        for (int j = 0; j < 8; j++) fsum += v[j]*fvp[kk*8 + j];
      }
      uint4 pk;
      pk.x = (u32)b[0] | ((u32)b[1] << 16);
      pk.y = (u32)b[2] | ((u32)b[3] << 16);
      pk.z = (u32)b[4] | ((u32)b[5] << 16);
      pk.w = (u32)b[6] | ((u32)b[7] << 16);
      *(uint4*)(LT + tid*144 + kk*16) = pk;
    }
    if (J.fout) atomicAdd(J.fout + (size_t)z*J.N + n, fsum);
    __syncthreads();

    // phase 2: redistribute; 8 lanes cover one row's 128B contiguously
    u16* obase = J.out + (size_t)z*J.K*J.N + (size_t)(ntile*256)*J.K + k0;
    #pragma unroll 2
    for (int cc = 0; cc < 8; cc++){
      const int g = cc*256 + tid;
      const int row = g >> 3, ch = g & 7;
      uint4 v = *(const uint4*)(LT + row*144 + ch*16);
      *(uint4*)(obase + (size_t)row*J.K + ch*8) = v;
    }
    return;
  }

  // ---------------- LN + gate + top-2 path ----------------
  __shared__ float xs[DM];
  __shared__ float sred[4], ssred[4];
  __shared__ float sc[NE];
  const int t = bid - ln_base;

  float2 v = reinterpret_cast<const float2*>(x + (size_t)t*DM)[tid];
  xs[2*tid]   = v.x;
  xs[2*tid+1] = v.y;
  float s  = v.x + v.y;
  float ss = v.x*v.x + v.y*v.y;
  #pragma unroll
  for (int o = 32; o > 0; o >>= 1){ s += __shfl_xor(s, o); ss += __shfl_xor(ss, o); }
  const int wid = tid >> 6, lane = tid & 63;
  if (lane == 0){ sred[wid] = s; ssred[wid] = ss; }
  __syncthreads();
  const float tot = sred[0]+sred[1]+sred[2]+sred[3];
  const float tss = ssred[0]+ssred[1]+ssred[2]+ssred[3];
  const float mu  = tot * (1.f/DM);
  const float var = tss * (1.f/DM) - mu*mu;
  const float rstd = rsqrtf(var + 1e-5f);
  u32 pk = (u32)f2bf((v.x-mu)*rstd) | ((u32)f2bf((v.y-mu)*rstd) << 16);
  *(u32*)(nxb + (size_t)t*DM + 2*tid) = pk;

  const int e = tid >> 2, sub = tid & 3;
  const float4* wrow4 = reinterpret_cast<const float4*>(Wg + (size_t)e*DM);
  const float4* xs4   = reinterpret_cast<const float4*>(xs);
  float acc = 0.f;
  #pragma unroll 4
  for (int i = sub; i < DM/4; i += 4){
    const float4 w = wrow4[i]; const float4 xv = xs4[i];
    acc += xv.x*w.x + xv.y*w.y + xv.z*w.z + xv.w*w.w;
  }
  acc += __shfl_xor(acc, 1);
  acc += __shfl_xor(acc, 2);
  if (sub == 0) sc[e] = acc + bg[e];
  __syncthreads();

  if (tid < 64) {
    const float s0 = sc[tid];
    float m = s0; int mi = tid;
    #pragma unroll
    for (int o = 1; o < 64; o <<= 1){
      float om = __shfl_xor(m, o); int oi = __shfl_xor(mi, o);
      if (om > m || (om == m && oi < mi)) { m = om; mi = oi; }
    }
    float s1 = (tid == mi) ? -INFINITY : s0;
    float m2 = s1; int mi2 = tid;
    #pragma unroll
    for (int o = 1; o < 64; o <<= 1){
      float om = __shfl_xor(m2, o); int oi = __shfl_xor(mi2, o);
      if (om > m2 || (om == m2 && oi < mi2)) { m2 = om; mi2 = oi; }
    }
    if (tid == 0){
      const float w0 = sig_(m), w1 = sig_(m2);
      const float inv = 1.f/(w0+w1);
      top_idx[2*t]   = mi;
      top_idx[2*t+1] = mi2;
      top_w[2*t]     = w0*inv;
      top_w[2*t+1]   = w1*inv;
    }
  }
}

// ---------------------------------------------------------------------------
// Kernel 2: routing. Padded (M=128) per-expert bases, scatter, tile list.
// ---------------------------------------------------------------------------
__global__ __launch_bounds__(256) void k_route(
    const int* __restrict__ top_idx, const float* __restrict__ top_w,
    int* __restrict__ bucket_tok, float* __restrict__ bucket_w,
    int* __restrict__ tiles, int* __restrict__ n_tiles)
{
  __shared__ int cnt[NE], base_[NE];
  __shared__ int nroute;
  const int tid = threadIdx.x;
  if (tid < NE) cnt[tid] = 0;
  __syncthreads();
  for (int p = tid; p < TT*2; p += 256) atomicAdd(&cnt[top_idx[p]], 1);
  __syncthreads();
  if (tid == 0){
    int run = 0, ntl = 0;
    for (int e = 0; e < NE; e++){
      base_[e] = run;
      const int c = cnt[e];
      for (int b = 0; b < c; b += 128){
        const int n = (c - b < 128) ? (c - b) : 128;
        tiles[ntl++] = (e << 17) | (((run + b) >> 7) << 8) | n;
      }
      run += ((c + 127) >> 7) << 7;   // padded advance
    }
    nroute = ntl;
    n_tiles[0] = ntl + NSH*(TT/128);
    n_tiles[1] = ntl;
  }
  __syncthreads();
  if (tid < NSH*(TT/128)){
    const int s = tid >> 5, t = tid & 31;     // TT/128 = 32
    const int b0 = PADBASE + s*TT + t*128;
    tiles[nroute + tid] = ((NE + s) << 17) | ((b0 >> 7) << 8) | 128;
  }
  if (tid < NE) cnt[tid] = 0;
  __syncthreads();
  for (int p = tid; p < TT*2; p += 256){
    const int e = top_idx[p];
    const int pos = base_[e] + atomicAdd(&cnt[e], 1);
    bucket_tok[pos] = p >> 1;
    bucket_w[pos]   = top_w[p];
  }
}

// ---------------------------------------------------------------------------
// Kernel 3: unified up-proj. M=128, N=128 (HE half via blockIdx.y), K=512,
// BK=32. 3-buffer counted-vmcnt pipeline + LDS XOR swizzle. 512 thr, 8 waves.
// ---------------------------------------------------------------------------
__global__ __launch_bounds__(512) void k_up(
    const u16* __restrict__ nxb,
    const u16* __restrict__ W1bT, const u16* __restrict__ W3bT,
    const u16* __restrict__ Ws1bT, const u16* __restrict__ Ws3bT,
    const float* __restrict__ b1, const float* __restrict__ b3,
    const float* __restrict__ bs1, const float* __restrict__ bs3,
    const float* __restrict__ b1f, const float* __restrict__ b3f,
    const int* __restrict__ bucket_tok, const float* __restrict__ bucket_w,
    const int* __restrict__ tiles, const int* __restrict__ n_tiles,
    u16* __restrict__ hrout, u16* __restrict__ hs)
{
  if ((int)blockIdx.x >= n_tiles[0]) return;
  const int info = tiles[blockIdx.x];
  const int e  = info >> 17;
  const int b0 = ((info >> 8) & 0x1FF) << 7;
  const int nt = info & 255;
  const bool sh = (e >= NE);
  const int y  = blockIdx.y;            // HE half

  __shared__ __align__(16) char Ab[3][8192];
  __shared__ __align__(16) char B1b[3][8192];
  __shared__ __align__(16) char B3b[3][8192];
  __shared__ int   toks[128];
  __shared__ float tw[128];

  const int tid = threadIdx.x, wid = tid >> 6, lane = tid & 63;
  const int l15 = lane & 15, q = lane >> 4;

  if (tid < 128){
    int tk; float w;
    if (!sh){
      if (tid < nt){ tk = bucket_tok[b0+tid]; w = bucket_w[b0+tid]; }
      else         { tk = 0; w = 0.f; }
    } else {
      tk = ((b0 - PADBASE) & (TT-1)) + tid; w = 1.f;
    }
    toks[tid] = tk; tw[tid] = w;
  }
  __syncthreads();

  const u16* w1e = sh ? (Ws1bT + (size_t)(e-NE)*HE*DM) : (W1bT + (size_t)e*HE*DM);
  const u16* w3e = sh ? (Ws3bT + (size_t)(e-NE)*HE*DM) : (W3bT + (size_t)e*HE*DM);

  const int srow = lane >> 2;
  const int csrc = (((lane & 3) ^ ((lane >> 3) & 3))) * 8;
  const u16* asrc = nxb + (size_t)toks[wid*16 + srow]*DM + csrc;
  const u16* b1s  = w1e + (size_t)(y*128 + wid*16 + srow)*DM + csrc;
  const u16* b3s  = w3e + (size_t)(y*128 + wid*16 + srow)*DM + csrc;
  const int loff = wid*1024;

#define UP_STAGE(ph, k0) do{ \
    gl16(asrc + (k0), Ab[ph] + loff); \
    gl16(b1s  + (k0), B1b[ph] + loff); \
    gl16(b3s  + (k0), B3b[ph] + loff); \
  } while(0)

  const int wm = (wid & 1)*64, wn = (wid >> 1)*32;

  const float* ob1 = sh ? (bs1 + (size_t)(e-NE)*HE) : (b1 + (size_t)e*HE);
  const float* ob3 = sh ? (bs3 + (size_t)(e-NE)*HE) : (b3 + (size_t)e*HE);
  f32x4 acc1[4][2], acc3[4][2];
  #pragma unroll
  for (int fn = 0; fn < 2; fn++){
    const int h = y*128 + wn + fn*16 + l15;
    const float v1 = ob1[h] + b1f[(size_t)e*HE + h];
    const float v3 = ob3[h] + b3f[(size_t)e*HE + h];
    #pragma unroll
    for (int fm = 0; fm < 4; fm++){
      acc1[fm][fn] = (f32x4){v1,v1,v1,v1};
      acc3[fm][fn] = (f32x4){v3,v3,v3,v3};
    }
  }

  UP_STAGE(0, 0);
  UP_STAGE(1, 32);
  const int csw = (q ^ ((l15 >> 1) & 3)) * 16;

  for (int ks = 0; ks < DM/32; ks++){
    const int cur = ks % 3;
    if (ks + 2 < DM/32) UP_STAGE((ks+2)%3, (ks+2)*32);
    if (ks < DM/32 - 2)       WAITV(6);
    else if (ks == DM/32 - 2) WAITV(3);
    else                      WAITV(0);
    SBAR();
    __builtin_amdgcn_s_setprio(1);
    const char* A  = Ab[cur];
    const char* B1 = B1b[cur];
    const char* B3 = B3b[cur];
    bf16x8 fa[4];
    #pragma unroll
    for (int fm = 0; fm < 4; fm++) fa[fm] = frd(A, wm + fm*16 + l15, csw);
    #pragma unroll
    for (int fn = 0; fn < 2; fn++){
      bf16x8 fb1 = frd(B1, wn + fn*16 + l15, csw);
      bf16x8 fb3 = frd(B3, wn + fn*16 + l15, csw);
      #pragma unroll
      for (int fm = 0; fm < 4; fm++){
        acc1[fm][fn] = mfma16(fa[fm], fb1, acc1[fm][fn]);
        acc3[fm][fn] = mfma16(fa[fm], fb3, acc3[fm][fn]);
      }
    }
    __builtin_amdgcn_s_setprio(0);
    SCHEDB();
    SBAR();
  }
#undef UP_STAGE

  const int tbase = sh ? ((b0 - PADBASE) & (TT-1)) : 0;
  const int scol  = sh ? (e - NE)*HE : 0;
  #pragma unroll
  for (int fm = 0; fm < 4; fm++){
    #pragma unroll
    for (int fn = 0; fn < 2; fn++){
      const int hl = y*128 + wn + fn*16 + l15;
      #pragma unroll
      for (int r = 0; r < 4; r++){
        const int m = wm + fm*16 + 4*q + r;
        float v = 0.f;
        if (m < nt){
          const float a1 = acc1[fm][fn][r];
          const float a3 = acc3[fm][fn][r];
          v = a1 * sig_(a1) * a3 * tw[m];
        }
        if (sh) hs[(size_t)(tbase+m)*HSH + scol + hl] = f2bf(v);
        else    hrout[(size_t)(b0+m)*HE + hl] = f2bf(v);
      }
    }
  }
}

// ---------------------------------------------------------------------------
// Kernel 4 (merged down): out was memset to 0; both paths atomicAdd.
//  blocks [0,128):   shared down. M=128 (t), N=128 (d), K=2048.
//  blocks [128,384): routed down. M=128 slots, N=256 (DM half), K=256.
// 512 threads, 8 waves (2M x 4N).
// ---------------------------------------------------------------------------
__global__ __launch_bounds__(512) void k_down(
    const u16* __restrict__ hs, const u16* __restrict__ Ws2bT,
    const float* __restrict__ bs2,
    const u16* __restrict__ hrout, const u16* __restrict__ W2bT,
    const float* __restrict__ b2,
    const int* __restrict__ bucket_tok, const float* __restrict__ bucket_w,
    const int* __restrict__ tiles, const int* __restrict__ n_tiles,
    float* __restrict__ out)
{
  __shared__ __align__(16) char LDS[73728];   // max(3*8K+3*8K, 3*8K+3*16K)
  __shared__ int   toks[128];
  __shared__ float tw[128];

  const int tid = threadIdx.x, wid = tid >> 6, lane = tid & 63;
  const int l15 = lane & 15, q = lane >> 4;
  const int csw  = (q ^ ((l15 >> 1) & 3)) * 16;
  const int srow = tid >> 2;
  const int csrc = ((tid & 3) ^ ((tid >> 3) & 3)) * 8;
  const int loff = wid*1024;

  if ((int)blockIdx.x < 128){
    // ---------------- shared expert down ----------------
    const int t0 = (blockIdx.x >> 2) * 128;
    const int d0 = (blockIdx.x & 3) * 128;
    char* Ab = LDS;            // 3 x 8192
    char* Bb = LDS + 24576;    // 3 x 8192

    const u16* asrc = hs    + (size_t)(t0 + srow)*HSH + csrc;
    const u16* bsrc = Ws2bT + (size_t)(d0 + srow)*HSH + csrc;

#define DS_STAGE(ph, k0) do{ \
    gl16(asrc + (k0), Ab + (ph)*8192 + loff); \
    gl16(bsrc + (k0), Bb + (ph)*8192 + loff); \
  } while(0)

    const int wm = (wid & 1)*64, wn = (wid >> 1)*32;

    f32x4 acc[4][2];
    #pragma unroll
    for (int fm = 0; fm < 4; fm++)
      #pragma unroll
      for (int fn = 0; fn < 2; fn++) acc[fm][fn] = (f32x4){0.f,0.f,0.f,0.f};

    DS_STAGE(0, 0);
    DS_STAGE(1, 32);

    for (int ks = 0; ks < HSH/32; ks++){
      const int cur = ks % 3;
      if (ks + 2 < HSH/32) DS_STAGE((ks+2)%3, (ks+2)*32);
      if (ks < HSH/32 - 2)       WAITV(4);
      else if (ks == HSH/32 - 2) WAITV(2);
      else                       WAITV(0);
      SBAR();
      __builtin_amdgcn_s_setprio(1);
      const char* A = Ab + cur*8192;
      const char* B = Bb + cur*8192;
      bf16x8 fa[4];
      #pragma unroll
      for (int fm = 0; fm < 4; fm++) fa[fm] = frd(A, wm + fm*16 + l15, csw);
      #pragma unroll
      for (int fn = 0; fn < 2; fn++){
        bf16x8 fb = frd(B, wn + fn*16 + l15, csw);
        #pragma unroll
        for (int fm = 0; fm < 4; fm++)
          acc[fm][fn] = mfma16(fa[fm], fb, acc[fm][fn]);
      }
      __builtin_amdgcn_s_setprio(0);
      SCHEDB();
      SBAR();
    }
#undef DS_STAGE

    #pragma unroll
    for (int fm = 0; fm < 4; fm++){
      #pragma unroll
      for (int fn = 0; fn < 2; fn++){
        const int d = d0 + wn + fn*16 + l15;
        const float bv = bs2[d];
        #pragma unroll
        for (int r = 0; r < 4; r++){
          const int t = t0 + wm + fm*16 + 4*q + r;
          atomicAdd(out + (size_t)t*DM + d, acc[fm][fn][r] + bv);
        }
      }
    }
    return;
  }

  // ---------------- routed down ----------------
  const int rb = (int)blockIdx.x - 128;
  const int ti = rb >> 1;
  if (ti >= n_tiles[1]) return;
  const int info = tiles[ti];
  const int e  = info >> 17;
  const int b0 = ((info >> 8) & 0x1FF) << 7;
  const int nt = info & 255;
  const int d0 = (rb & 1) * 256;

  char* Ab = LDS;            // 3 x 8192
  char* Bb = LDS + 24576;    // 3 x 16384

  if (tid < 128){
    if (tid < nt){ toks[tid] = bucket_tok[b0+tid]; tw[tid] = bucket_w[b0+tid]; }
    else         { toks[tid] = 0; tw[tid] = 0.f; }
  }
  __syncthreads();

  const u16* w2e = W2bT + (size_t)e*DM*HE;
  const u16* asrc  = hrout + (size_t)(b0 + srow)*HE + csrc;
  const u16* bsrc0 = w2e + (size_t)(d0 + srow)*HE + csrc;
  const u16* bsrc1 = w2e + (size_t)(d0 + 128 + srow)*HE + csrc;

#define DR_STAGE(ph, k0) do{ \
    gl16(asrc  + (k0), Ab + (ph)*8192  + loff); \
    gl16(bsrc0 + (k0), Bb + (ph)*16384 + loff); \
    gl16(bsrc1 + (k0), Bb + (ph)*16384 + 8192 + loff); \
  } while(0)

  const int wm = (wid & 1)*64, wn = (wid >> 1)*64;

  f32x4 acc[4][4];
  #pragma unroll
  for (int fm = 0; fm < 4; fm++)
    #pragma unroll
    for (int fn = 0; fn < 4; fn++) acc[fm][fn] = (f32x4){0.f,0.f,0.f,0.f};

  DR_STAGE(0, 0);
  DR_STAGE(1, 32);

  for (int ks = 0; ks < HE/32; ks++){
    const int cur = ks % 3;
    if (ks + 2 < HE/32) DR_STAGE((ks+2)%3, (ks+2)*32);
    if (ks < HE/32 - 2)       WAITV(6);
    else if (ks == HE/32 - 2) WAITV(3);
    else                      WAITV(0);
    SBAR();
    __builtin_amdgcn_s_setprio(1);
    const char* A = Ab + cur*8192;
    const char* B = Bb + cur*16384;
    bf16x8 fa[4];
    #pragma unroll
    for (int fm = 0; fm < 4; fm++) fa[fm] = frd(A, wm + fm*16 + l15, csw);
    #pragma unroll
    for (int fn = 0; fn < 4; fn++){
      bf16x8 fb = frd(B, wn + fn*16 + l15, csw);
      #pragma unroll
      for (int fm = 0; fm < 4; fm++)
        acc[fm][fn] = mfma16(fa[fm], fb, acc[fm][fn]);
    }
    __builtin_amdgcn_s_setprio(0);
    SCHEDB();
    SBAR();
  }
#undef DR_STAGE

  #pragma unroll
  for (int fm = 0; fm < 4; fm++){
    #pragma unroll
    for (int fn = 0; fn < 4; fn++){
      const int d = d0 + wn + fn*16 + l15;
      #pragma unroll
      for (int r = 0; r < 4; r++){
        const int m = wm + fm*16 + 4*q + r;
        if (m < nt)
          atomicAdd(out + (size_t)toks[m]*DM + d, acc[fm][fn][r] + tw[m]*b2[(size_t)e*DM + d]);
      }
    }
  }
}

// ---------------------------------------------------------------------------
extern "C" void kernel_launch(void* const* d_in, const int* in_sizes, int n_in,
                              void* d_out, int out_size, void* d_ws, size_t ws_size,
                              hipStream_t stream)
{
  (void)in_sizes; (void)n_in; (void)ws_size;
  const float* x     = (const float*)d_in[0];
  const float* Wg    = (const float*)d_in[1];
  const float* bg    = (const float*)d_in[2];
  const float* gamma = (const float*)d_in[3];
  const float* beta  = (const float*)d_in[4];
  const float* W1    = (const float*)d_in[5];
  const float* b1    = (const float*)d_in[6];
  const float* W3    = (const float*)d_in[7];
  const float* b3    = (const float*)d_in[8];
  const float* W2    = (const float*)d_in[9];
  const float* b2    = (const float*)d_in[10];
  const float* gs    = (const float*)d_in[11];
  const float* bs    = (const float*)d_in[12];
  const float* Ws1   = (const float*)d_in[13];
  const float* bs1   = (const float*)d_in[14];
  const float* Ws3   = (const float*)d_in[15];
  const float* bs3   = (const float*)d_in[16];
  const float* Ws2   = (const float*)d_in[17];
  const float* bs2   = (const float*)d_in[18];
  float* out = (float*)d_out;

  char* ws = (char*)d_ws;
  size_t off = 0;
  auto alloc = [&](size_t bytes) -> char* {
    char* p = ws + off;
    off += (bytes + 255) & ~(size_t)255;
    return p;
  };
  u16*   nxb        = (u16*)  alloc((size_t)TT*DM*2);
  int*   top_idx    = (int*)  alloc((size_t)TT*2*4);
  float* top_w      = (float*)alloc((size_t)TT*2*4);
  int*   bucket_tok = (int*)  alloc((size_t)PADBASE*4);
  float* bucket_w   = (float*)alloc((size_t)PADBASE*4);
  int*   tiles      = (int*)  alloc(MAXTILES*4);
  int*   n_tiles    = (int*)  alloc(64);
  u16*   hrout      = (u16*)  alloc((size_t)PADBASE*HE*2);
  u16*   hs         = (u16*)  alloc((size_t)TT*HSH*2);
  u16*   W1bT       = (u16*)  alloc((size_t)NE*HE*DM*2);
  u16*   W3bT       = (u16*)  alloc((size_t)NE*HE*DM*2);
  u16*   W2bT       = (u16*)  alloc((size_t)NE*DM*HE*2);
  u16*   Ws1bT      = (u16*)  alloc((size_t)HSH*DM*2);
  u16*   Ws3bT      = (u16*)  alloc((size_t)HSH*DM*2);
  u16*   Ws2bT      = (u16*)  alloc((size_t)DM*HSH*2);
  float* b1f        = (float*)alloc((size_t)(NE*HE + HSH)*4);
  float* b3f        = (float*)alloc((size_t)(NE*HE + HSH)*4);

  // --- memsets ---
  hipMemsetAsync(b1f, 0, (size_t)(NE*HE + HSH)*4, stream);
  hipMemsetAsync(b3f, 0, (size_t)(NE*HE + HSH)*4, stream);
  hipMemsetAsync(out, 0, (size_t)out_size*sizeof(float), stream);

  // --- fused pre-pass: convert/transpose + folds + LN/gate (one launch) ---
  CvtJobs jobs;
  // bases: blocks per job = Z * (K/64) * (N/256)
  jobs.j[0] = { W1,  gamma,   beta,    W1bT,  b1f,          DM,  HE,  0    }; // 512
  jobs.j[1] = { W3,  gamma,   beta,    W3bT,  b3f,          DM,  HE,  512  }; // 512
  jobs.j[2] = { W2,  nullptr, nullptr, W2bT,  nullptr,      HE,  DM,  1024 }; // 512
  jobs.j[3] = { Ws1, gs,      bs,      Ws1bT, b1f + NE*HE,  DM,  HSH, 1536 }; // 64
  jobs.j[4] = { Ws3, gs,      bs,      Ws3bT, b3f + NE*HE,  DM,  HSH, 1600 }; // 64
  jobs.j[5] = { Ws2, nullptr, nullptr, Ws2bT, nullptr,      HSH, DM,  1664 }; // 64
  const int ln_base = 1728;
  k_pre<<<dim3(ln_base + TT), 256, 0, stream>>>(jobs, ln_base,
                                                x, Wg, bg, nxb, top_idx, top_w);

  // --- routing ---
  k_route<<<dim3(1), 256, 0, stream>>>(top_idx, top_w, bucket_tok, bucket_w, tiles, n_tiles);

  // --- expert GEMMs ---
  k_up<<<dim3(MAXTILES, 2), 512, 0, stream>>>(nxb, W1bT, W3bT, Ws1bT, Ws3bT,
                                              b1, b3, bs1, bs3, b1f, b3f,
                                              bucket_tok, bucket_w, tiles, n_tiles, hrout, hs);
  k_down<<<dim3(384), 512, 0, stream>>>(hs, Ws2bT, bs2, hrout, W2bT, b2,
                                        bucket_tok, bucket_w, tiles, n_tiles, out);
}